// Round 1
// baseline (91.346 us; speedup 1.0000x reference)
//
#include <hip/hip_runtime.h>
#include <stdint.h>

#define S_LEN 2048
#define NH 8
#define HD 64
#define W 64
#define TQ 32        // queries per block
#define ROWS 160     // TQ + 2*W
#define LDK 68       // padded K row stride in floats (breaks pow2 bank stride)

__device__ __forceinline__ float rdlane(float v, int l) {
  return __int_as_float(__builtin_amdgcn_readlane(__float_as_int(v), l));
}
__device__ __forceinline__ float b2f(uint16_t v) {
  return __uint_as_float(((uint32_t)v) << 16);
}
__device__ __forceinline__ uint16_t f2b(float f) {   // RTNE fp32 -> bf16
  uint32_t u = __float_as_uint(f);
  u += 0x7FFFu + ((u >> 16) & 1u);
  return (uint16_t)(u >> 16);
}
__device__ __forceinline__ float wave_max(float v) {
#pragma unroll
  for (int m = 32; m >= 1; m >>= 1) v = fmaxf(v, __shfl_xor(v, m, 64));
  return v;
}
__device__ __forceinline__ float wave_sum(float v) {
#pragma unroll
  for (int m = 32; m >= 1; m >>= 1) v += __shfl_xor(v, m, 64);
  return v;
}

__global__ __launch_bounds__(256, 2)
void swa_kernel(const float* __restrict__ Q, const float* __restrict__ K,
                const float* __restrict__ V, float* __restrict__ O) {
  __shared__ float    Ks[ROWS * LDK];   // 43,520 B
  __shared__ uint16_t Vs[ROWS * HD];    // 20,480 B  (total 64,000 B)

  const int tile = blockIdx.x;          // 0..63
  const int h    = blockIdx.y;          // 0..7
  const int tid  = threadIdx.x;
  const int g0   = tile * TQ - W;       // global seq row of lds row 0

  // ---- stage K (fp32, padded stride) and V (bf16), zero-fill OOB rows ----
#pragma unroll
  for (int it = 0; it < 10; ++it) {
    int idx = tid + it * 256;           // 0..2559 : row = idx/16, float4-chunk = idx%16
    int row = idx >> 4;
    int c   = idx & 15;
    int g   = g0 + row;
    float4 kv = make_float4(0.f, 0.f, 0.f, 0.f);
    float4 vv = make_float4(0.f, 0.f, 0.f, 0.f);
    if ((unsigned)g < (unsigned)S_LEN) {
      const float* kp = K + ((g * NH + h) << 6) + (c << 2);
      const float* vp = V + ((g * NH + h) << 6) + (c << 2);
      kv = *(const float4*)kp;
      vv = *(const float4*)vp;
    }
    *(float4*)&Ks[row * LDK + (c << 2)] = kv;
    ushort4 pk;
    pk.x = f2b(vv.x); pk.y = f2b(vv.y); pk.z = f2b(vv.z); pk.w = f2b(vv.w);
    *(ushort4*)&Vs[row * HD + (c << 2)] = pk;
  }
  __syncthreads();

  const int lane = tid & 63;
  const int qb   = (tid >> 6) * 8;      // wave's first local query (0,8,16,24)
  const int s0   = tile * TQ + qb;      // global qpos of this wave's query i=0

  // per-lane q values for the wave's 8 queries (lane == d)
  float qv[8];
#pragma unroll
  for (int i = 0; i < 8; ++i)
    qv[i] = Q[(((s0 + i) * NH + h) << 6) + lane] * 0.125f;

  // lane l covers lds rows qb+l, qb+64+l, qb+128+l (shared across 8 queries)
  const float* ka = &Ks[(qb + lane) * LDK];
  const float* kb = &Ks[(qb + 64 + lane) * LDK];
  int rc = qb + 128 + lane; if (rc > ROWS - 1) rc = ROWS - 1;  // clamp, invalid lanes masked
  const float* kc = &Ks[rc * LDK];

  float sa[8], sb[8], sc[8];
#pragma unroll
  for (int i = 0; i < 8; ++i) { sa[i] = 0.f; sb[i] = 0.f; sc[i] = 0.f; }

#pragma unroll 4
  for (int d = 0; d < 64; d += 4) {
    float4 A  = *(const float4*)(ka + d);
    float4 Bv = *(const float4*)(kb + d);
    float4 Cv = *(const float4*)(kc + d);
#pragma unroll
    for (int i = 0; i < 8; ++i) {
      float q0 = rdlane(qv[i], d + 0);
      float q1 = rdlane(qv[i], d + 1);
      float q2 = rdlane(qv[i], d + 2);
      float q3 = rdlane(qv[i], d + 3);
      sa[i] = fmaf(q0, A.x,  sa[i]); sa[i] = fmaf(q1, A.y,  sa[i]);
      sa[i] = fmaf(q2, A.z,  sa[i]); sa[i] = fmaf(q3, A.w,  sa[i]);
      sb[i] = fmaf(q0, Bv.x, sb[i]); sb[i] = fmaf(q1, Bv.y, sb[i]);
      sb[i] = fmaf(q2, Bv.z, sb[i]); sb[i] = fmaf(q3, Bv.w, sb[i]);
      sc[i] = fmaf(q0, Cv.x, sc[i]); sc[i] = fmaf(q1, Cv.y, sc[i]);
      sc[i] = fmaf(q2, Cv.z, sc[i]); sc[i] = fmaf(q3, Cv.w, sc[i]);
    }
  }

  // ---- softmax: per query i, lane l holds offsets l-i-64, l-i, 64+l-i ----
  float ea[8], eb[8], ec[8], rsum[8];
#pragma unroll
  for (int i = 0; i < 8; ++i) {
    bool va = (lane >= i) && ((s0 - 64 + lane) >= 0);
    bool vb = (s0 + lane) < S_LEN;
    bool vc = (lane <= i) && ((s0 + 64 + lane) < S_LEN);
    float m3 = fmaxf(fmaxf(va ? sa[i] : -INFINITY, vb ? sb[i] : -INFINITY),
                     vc ? sc[i] : -INFINITY);
    float mx = wave_max(m3);
    ea[i] = va ? __expf(sa[i] - mx) : 0.f;
    eb[i] = vb ? __expf(sb[i] - mx) : 0.f;
    ec[i] = vc ? __expf(sc[i] - mx) : 0.f;
    float sm = wave_sum(ea[i] + eb[i] + ec[i]);
    rsum[i] = 1.0f / sm;
  }

  // ---- PV: row qb+j pairs with weight-lane j of every query (shared reads) ----
  float acc[8];
#pragma unroll
  for (int i = 0; i < 8; ++i) acc[i] = 0.f;

  const uint16_t* vpa = &Vs[qb * HD + lane];
#pragma unroll 4
  for (int j = 0; j < 64; ++j) {
    float vv = b2f(vpa[j * HD]);
#pragma unroll
    for (int i = 0; i < 8; ++i) acc[i] = fmaf(rdlane(ea[i], j), vv, acc[i]);
  }
  const uint16_t* vpb = vpa + 64 * HD;
#pragma unroll 4
  for (int j = 0; j < 64; ++j) {
    float vv = b2f(vpb[j * HD]);
#pragma unroll
    for (int i = 0; i < 8; ++i) acc[i] = fmaf(rdlane(eb[i], j), vv, acc[i]);
  }
  const uint16_t* vpc = vpa + 128 * HD;
#pragma unroll
  for (int j = 0; j < 8; ++j) {
    float vv = b2f(vpc[j * HD]);
#pragma unroll
    for (int i = 0; i < 8; ++i) acc[i] = fmaf(rdlane(ec[i], j), vv, acc[i]);
  }

#pragma unroll
  for (int i = 0; i < 8; ++i)
    O[(((s0 + i) * NH + h) << 6) + lane] = acc[i] * rsum[i];
}

extern "C" void kernel_launch(void* const* d_in, const int* in_sizes, int n_in,
                              void* d_out, int out_size, void* d_ws, size_t ws_size,
                              hipStream_t stream) {
  const float* Q = (const float*)d_in[0];
  const float* K = (const float*)d_in[1];
  const float* V = (const float*)d_in[2];
  float* O = (float*)d_out;
  dim3 grid(S_LEN / TQ, NH);
  swa_kernel<<<grid, 256, 0, stream>>>(Q, K, V, O);
}

// Round 2
// 79.348 us; speedup vs baseline: 1.1512x; 1.1512x over previous
//
#include <hip/hip_runtime.h>
#include <stdint.h>

#define S_LEN 2048
#define NH    8
#define TQ    32            // queries per block
#define NKV   160           // K/V window rows per block (TQ + 2*64)
#define SS    161           // score LDS stride (fp32)  -> odd dword stride, clean banks
#define PP    168           // P LDS stride (bf16): 336 B = 21*16 -> b128-aligned rows
#define PVT   168           // Vt LDS stride (bf16), same property

typedef __attribute__((ext_vector_type(8))) short  short8;   // 8 bf16 (4 VGPRs)
typedef __attribute__((ext_vector_type(4))) float  floatx4;  // MFMA C/D

__device__ __forceinline__ uint16_t f2b(float f) {           // RTNE fp32 -> bf16
  uint32_t u = __float_as_uint(f);
  u += 0x7FFFu + ((u >> 16) & 1u);
  return (uint16_t)(u >> 16);
}
__device__ __forceinline__ short8 pack8(float4 a, float4 b) {
  short8 r;
  r[0] = (short)f2b(a.x); r[1] = (short)f2b(a.y);
  r[2] = (short)f2b(a.z); r[3] = (short)f2b(a.w);
  r[4] = (short)f2b(b.x); r[5] = (short)f2b(b.y);
  r[6] = (short)f2b(b.z); r[7] = (short)f2b(b.w);
  return r;
}
__device__ __forceinline__ float wave_max(float v) {
#pragma unroll
  for (int m = 32; m >= 1; m >>= 1) v = fmaxf(v, __shfl_xor(v, m, 64));
  return v;
}
__device__ __forceinline__ float wave_sum(float v) {
#pragma unroll
  for (int m = 32; m >= 1; m >>= 1) v += __shfl_xor(v, m, 64);
  return v;
}

__global__ __launch_bounds__(256, 2)
void swa_mfma(const float* __restrict__ Q, const float* __restrict__ K,
              const float* __restrict__ V, float* __restrict__ O) {
  __shared__ float    Ssc[TQ * SS];      // 20,608 B  raw scores (fp32)
  __shared__ uint16_t Pw [TQ * PP];      // 10,752 B  normalized probs (bf16)
  __shared__ uint16_t Vt [64 * PVT];     // 21,504 B  V transposed: Vt[d][kpos] (bf16)

  const int tile = blockIdx.x;           // 0..63
  const int h    = blockIdx.y;           // 0..7
  const int tid  = threadIdx.x;
  const int g0   = tile * TQ - 64;       // global kpos of local col 0

  // ---------- stage V transposed into LDS (clamp rows; masked by P=0 later) ----------
#pragma unroll
  for (int it = 0; it < 10; ++it) {
    int task = tid + it * 256;           // 2560 tasks: 64 d x 40 col-quads
    int d    = task & 63;
    int cq   = task >> 6;                // 0..39
    int gb   = g0 + (cq << 2);
    float v[4];
#pragma unroll
    for (int k = 0; k < 4; ++k) {
      int g = gb + k;
      g = g < 0 ? 0 : (g > S_LEN - 1 ? S_LEN - 1 : g);
      v[k] = V[((g * NH + h) << 6) + d];           // coalesced along d
    }
    uint32_t p01 = (uint32_t)f2b(v[0]) | ((uint32_t)f2b(v[1]) << 16);
    uint32_t p23 = (uint32_t)f2b(v[2]) | ((uint32_t)f2b(v[3]) << 16);
    uint32_t* dst = (uint32_t*)&Vt[d * PVT + (cq << 2)];
    dst[0] = p01; dst[1] = p23;
  }

  // ---------- phase 1: QK^T via MFMA, scores -> LDS ----------
  const int lane = tid & 63;
  const int w    = tid >> 6;
  const int r16  = lane & 15;
  const int quad = lane >> 4;
  const int m    = w & 1;                // wave's query m-tile (0/1)
  const int n0   = w >> 1;               // wave's first n-tile

  // Q A-frags (two k-halves), scaled by 1/sqrt(64)
  const int qrow = tile * TQ + m * 16 + r16;
  const float* qb = Q + ((qrow * NH + h) << 6) + (quad << 3);
  float4 q0 = *(const float4*)(qb);
  float4 q1 = *(const float4*)(qb + 4);
  float4 q2 = *(const float4*)(qb + 32);
  float4 q3 = *(const float4*)(qb + 36);
  const float sc = 0.125f;
  q0.x*=sc;q0.y*=sc;q0.z*=sc;q0.w*=sc;  q1.x*=sc;q1.y*=sc;q1.z*=sc;q1.w*=sc;
  q2.x*=sc;q2.y*=sc;q2.z*=sc;q2.w*=sc;  q3.x*=sc;q3.y*=sc;q3.z*=sc;q3.w*=sc;
  short8 aq0 = pack8(q0, q1);
  short8 aq1 = pack8(q2, q3);

#pragma unroll
  for (int u = 0; u < 5; ++u) {
    int nt = n0 + 2 * u;                 // this wave's n-tiles (5 of 10)
    int g  = g0 + nt * 16 + r16;         // kpos row for B-frag
    g = g < 0 ? 0 : (g > S_LEN - 1 ? S_LEN - 1 : g);   // clamp: finite garbage, masked later
    const float* kb = K + ((g * NH + h) << 6) + (quad << 3);
    float4 k0 = *(const float4*)(kb);
    float4 k1 = *(const float4*)(kb + 4);
    float4 k2 = *(const float4*)(kb + 32);
    float4 k3 = *(const float4*)(kb + 36);
    short8 b0 = pack8(k0, k1);
    short8 b1 = pack8(k2, k3);
    floatx4 acc = {0.f, 0.f, 0.f, 0.f};
    acc = __builtin_amdgcn_mfma_f32_16x16x32_bf16(aq0, b0, acc, 0, 0, 0);
    acc = __builtin_amdgcn_mfma_f32_16x16x32_bf16(aq1, b1, acc, 0, 0, 0);
    int colbase = nt * 16 + r16;
    int rowbase = m * 16 + quad * 4;     // C/D: row = quad*4 + reg, col = lane&15
#pragma unroll
    for (int rg = 0; rg < 4; ++rg)
      Ssc[(rowbase + rg) * SS + colbase] = acc[rg];
  }
  __syncthreads();

  // ---------- phase 2: softmax over 160 cols, normalized bf16 P -> LDS ----------
#pragma unroll
  for (int k = 0; k < 8; ++k) {
    int r  = w * 8 + k;                  // local query row 0..31
    int lo = r;                          // valid cols: [r, r+128] ∩ seq bounds
    int t0 = 64 - tile * TQ;  if (t0 > lo) lo = t0;
    int hi = r + 128;
    int t1 = (S_LEN - 1) - g0; if (t1 < hi) hi = t1;
    const float* Sr = &Ssc[r * SS];
    int c0 = lane, c1 = lane + 64, c2 = lane + 128;
    int c2c = c2 > 160 ? 160 : c2;       // clamp read/write into pad col
    float s0v = Sr[c0], s1v = Sr[c1], s2v = Sr[c2c];
    bool v0 = (c0 >= lo) && (c0 <= hi);
    bool v1 = (c1 >= lo) && (c1 <= hi);
    bool v2 = (c2 >= lo) && (c2 <= hi);
    float mx = wave_max(fmaxf(fmaxf(v0 ? s0v : -INFINITY, v1 ? s1v : -INFINITY),
                              v2 ? s2v : -INFINITY));
    float e0 = v0 ? __expf(s0v - mx) : 0.f;
    float e1 = v1 ? __expf(s1v - mx) : 0.f;
    float e2 = v2 ? __expf(s2v - mx) : 0.f;
    float rs = 1.0f / wave_sum(e0 + e1 + e2);
    uint16_t* Pr = &Pw[r * PP];
    Pr[c0]  = f2b(e0 * rs);
    Pr[c1]  = f2b(e1 * rs);
    Pr[c2c] = f2b(e2 * rs);              // invalid lanes write 0 into pad col 160
  }
  __syncthreads();

  // ---------- phase 3: O = P·V via MFMA ----------
  short8 pa[5];
  const uint16_t* Prow = &Pw[(m * 16 + r16) * PP + (quad << 3)];
#pragma unroll
  for (int kq = 0; kq < 5; ++kq)
    pa[kq] = *(const short8*)(Prow + kq * 32);   // A-frag: P[m][k], 16B aligned

#pragma unroll
  for (int t = 0; t < 2; ++t) {
    int nt = n0 + 2 * t;                 // d-tile (0..3), 2 per wave
    const uint16_t* Vrow = &Vt[(nt * 16 + r16) * PVT + (quad << 3)];
    floatx4 o = {0.f, 0.f, 0.f, 0.f};
#pragma unroll
    for (int kq = 0; kq < 5; ++kq) {
      short8 bv = *(const short8*)(Vrow + kq * 32);  // B-frag: V[k][n=d]
      o = __builtin_amdgcn_mfma_f32_16x16x32_bf16(pa[kq], bv, o, 0, 0, 0);
    }
    int orow = tile * TQ + m * 16 + quad * 4;
    int d    = nt * 16 + r16;
#pragma unroll
    for (int rg = 0; rg < 4; ++rg)
      O[(((orow + rg) * NH + h) << 6) + d] = o[rg];
  }
}

extern "C" void kernel_launch(void* const* d_in, const int* in_sizes, int n_in,
                              void* d_out, int out_size, void* d_ws, size_t ws_size,
                              hipStream_t stream) {
  const float* Q = (const float*)d_in[0];
  const float* K = (const float*)d_in[1];
  const float* V = (const float*)d_in[2];
  float* O = (float*)d_out;
  dim3 grid(S_LEN / TQ, NH);
  swa_mfma<<<grid, 256, 0, stream>>>(Q, K, V, O);
}